// Round 11
// baseline (23320.421 us; speedup 1.0000x reference)
//
#include <hip/hip_runtime.h>
#include <math.h>

#define CC 1024
#define LL 2048
#define NWG 64
#define NT 1024
#define ELPW 16  // elements per WG (= waves per WG)

typedef float f4 __attribute__((ext_vector_type(4)));
typedef unsigned u2v __attribute__((ext_vector_type(2)));

// ws word layout:
// [0 .. 4095]      h0 packets: 2 parities x 1024 elems x 2 words (val, tag) [memset 0]
// [4096 .. 8191]   h1 packets: same layout                                  [memset 0]
// [8192 .. 10239]  gbar arrival epochs (64 x 32 words)                      [memset 0]
// [10240]          gbar release epoch                                       [memset 0]
// [10304 .. 12351] logits[2048]
// [12352 .. 13375] av[1024]
// tag = tau+1 written at tick tau, parity (tau+1)&1; exact-match poll.
#define H1_BASE 4096
#define PKT_PAR 2048
#define WS_FLAGS 8192
#define WS_REL 10240
#define WS_LOGITS 10304
#define WS_AV 12352
#define WS_MEMSET_BYTES ((WS_REL + 64) * 4)

__device__ __forceinline__ float aload(const float* p) {
  return __hip_atomic_load(p, __ATOMIC_RELAXED, __HIP_MEMORY_SCOPE_AGENT);
}
__device__ __forceinline__ void astore(float* p, float v) {
  __hip_atomic_store(p, v, __ATOMIC_RELAXED, __HIP_MEMORY_SCOPE_AGENT);
}
__device__ __forceinline__ float sigm(float x) { return 1.0f / (1.0f + __expf(-x)); }
__device__ __forceinline__ float tanh_(float x) { return 2.0f / (1.0f + __expf(-2.0f * x)) - 1.0f; }
__device__ __forceinline__ float dot4(f4 a, f4 b) {
  return fmaf(a.x, b.x, fmaf(a.y, b.y, fmaf(a.z, b.z, a.w * b.w)));
}

// 8B L2-bypass poll load (issue only)
__device__ __forceinline__ u2v ld8v(const unsigned* p) {
  u2v r;
  asm volatile("global_load_dwordx2 %0, %1, off sc0 sc1" : "=v"(r) : "v"(p) : "memory");
  return r;
}
__device__ __forceinline__ void vm0() { asm volatile("s_waitcnt vmcnt(0)" ::: "memory"); }
__device__ __forceinline__ void npause() { asm volatile("s_sleep 1" ::: "memory"); }

// publish: 8B (val,tag) agent-scope atomic swap (single-copy atomic at device scope)
__device__ __forceinline__ void pub8(unsigned* p, unsigned val, unsigned tag) {
  unsigned long long pk = (unsigned long long)val | ((unsigned long long)tag << 32);
  (void)__hip_atomic_exchange((unsigned long long*)p, pk, __ATOMIC_RELAXED,
                              __HIP_MEMORY_SCOPE_AGENT);
}

// prologue-only arrival-slot barrier (relaxed spins + one acquire)
__device__ __forceinline__ void gbar(unsigned* ws_u, unsigned epoch) {
  __syncthreads();
  if (blockIdx.x == 0) {
    const int i = threadIdx.x;
    if (i > 0 && i < NWG) {
      unsigned* slot = ws_u + WS_FLAGS + i * 32;
      while (__hip_atomic_load(slot, __ATOMIC_RELAXED, __HIP_MEMORY_SCOPE_AGENT) < epoch) {
      }
      (void)__hip_atomic_load(slot, __ATOMIC_ACQUIRE, __HIP_MEMORY_SCOPE_AGENT);
    }
    __syncthreads();
    if (i == 0)
      __hip_atomic_store(ws_u + WS_REL, epoch, __ATOMIC_RELEASE, __HIP_MEMORY_SCOPE_AGENT);
    __syncthreads();
  } else {
    if (threadIdx.x == 0) {
      __hip_atomic_store(ws_u + WS_FLAGS + blockIdx.x * 32, epoch, __ATOMIC_RELEASE,
                         __HIP_MEMORY_SCOPE_AGENT);
      unsigned* rel = ws_u + WS_REL;
      while (__hip_atomic_load(rel, __ATOMIC_RELAXED, __HIP_MEMORY_SCOPE_AGENT) < epoch) {
      }
      (void)__hip_atomic_load(rel, __ATOMIC_ACQUIRE, __HIP_MEMORY_SCOPE_AGENT);
    }
    __syncthreads();
  }
}

#define PIN12                                                                        \
  asm volatile("" : "+v"(Wa[0]), "+v"(Wa[1]), "+v"(Wa[2]), "+v"(Wa[3]), "+v"(Wa[4]), \
                    "+v"(Wa[5]), "+v"(Wa[6]), "+v"(Wa[7]), "+v"(Wa[8]), "+v"(Wa[9]), \
                    "+v"(Wa[10]), "+v"(Wa[11]))

__global__ __launch_bounds__(NT, 1) void decoder_kernel(
    const float* __restrict__ x, const float* __restrict__ attn_w,
    const float* __restrict__ w_ih0, const float* __restrict__ w_hh0,
    const float* __restrict__ b_ih0, const float* __restrict__ b_hh0,
    const float* __restrict__ w_ih1, const float* __restrict__ w_hh1,
    const float* __restrict__ b_ih1, const float* __restrict__ b_hh1,
    float* __restrict__ out, float* __restrict__ ws) {
  const int g = blockIdx.x;
  const int tid = threadIdx.x;
  const int lane = tid & 63;
  const int w = tid >> 6;        // wave 0..15
  const int eb = ELPW * g;       // first element of this WG
  const int eg = eb + w;         // element owned by this wave

  unsigned* ws_u = (unsigned*)ws;

  __shared__ __align__(16) float h0s[CC];
  __shared__ __align__(16) float h1s[CC];
  __shared__ float red[NT];
  __shared__ float cgi0[48], cbh0[48], cbh1[48], cbi1[48];

  // ---------- P0: logits[t] = dot(w2, x[t]) for this WG's 32 timesteps ----------
  {
    const float* w2 = attn_w + CC;
#pragma unroll
    for (int s = 0; s < 2; ++s) {
      int t = 32 * g + 2 * w + s;
      const float* xr = x + (size_t)t * CC;
      float p = 0.f;
#pragma unroll
      for (int k = 0; k < 4; ++k) {
        f4 xa = *(const f4*)(xr + 256 * k + 4 * lane);
        f4 wa = *(const f4*)(w2 + 256 * k + 4 * lane);
        p += dot4(xa, wa);
      }
#pragma unroll
      for (int off = 32; off; off >>= 1) p += __shfl_xor(p, off, 64);
      if (lane == 0) astore(ws + WS_LOGITS + t, p);
    }
  }
  gbar(ws_u, 1);

  // ---------- P1: softmax over L (replicated), av columns [eb, eb+16) ----------
  {
    float myl[2];
#pragma unroll
    for (int s = 0; s < 2; ++s) myl[s] = aload(ws + WS_LOGITS + tid + 1024 * s);
    float lm = fmaxf(myl[0], myl[1]);
#pragma unroll
    for (int off = 32; off; off >>= 1) lm = fmaxf(lm, __shfl_xor(lm, off, 64));
    if (lane == 0) red[w] = lm;
    __syncthreads();
    float m = red[0];
#pragma unroll
    for (int i = 1; i < 16; ++i) m = fmaxf(m, red[i]);
    float myw[2];
    myw[0] = __expf(myl[0] - m);
    myw[1] = __expf(myl[1] - m);
    float ls = myw[0] + myw[1];
#pragma unroll
    for (int off = 32; off; off >>= 1) ls += __shfl_xor(ls, off, 64);
    __syncthreads();
    if (lane == 0) red[16 + w] = ls;
    __syncthreads();
    float Z = 0.f;
#pragma unroll
    for (int i = 0; i < 16; ++i) Z += red[16 + i];
    float invZ = 1.0f / Z;
    // av partials: this thread's 2 timesteps, 16 columns
    float acc[16];
#pragma unroll
    for (int c = 0; c < 16; ++c) acc[c] = 0.f;
#pragma unroll
    for (int s = 0; s < 2; ++s) {
      int t = tid + 1024 * s;
      const float* xr = x + (size_t)t * CC + eb;
#pragma unroll
      for (int q = 0; q < 4; ++q) {
        f4 xa = *(const f4*)(xr + 4 * q);
        acc[4 * q + 0] = fmaf(myw[s], xa.x, acc[4 * q + 0]);
        acc[4 * q + 1] = fmaf(myw[s], xa.y, acc[4 * q + 1]);
        acc[4 * q + 2] = fmaf(myw[s], xa.z, acc[4 * q + 2]);
        acc[4 * q + 3] = fmaf(myw[s], xa.w, acc[4 * q + 3]);
      }
    }
#pragma unroll
    for (int c = 0; c < 16; ++c) {
#pragma unroll
      for (int off = 32; off; off >>= 1) acc[c] += __shfl_xor(acc[c], off, 64);
    }
    __syncthreads();
    if (lane == 0) {
#pragma unroll
      for (int c = 0; c < 16; ++c) red[256 + w * 16 + c] = acc[c];
    }
    __syncthreads();
    if (tid < 16) {
      float s = 0.f;
#pragma unroll
      for (int ww = 0; ww < 16; ++ww) s += red[256 + ww * 16 + tid];
      astore(ws + WS_AV + eb + tid, s * invZ);
    }
  }
  gbar(ws_u, 2);

  // ---------- P2: full av -> h0s; gi0 = W_ih0 . av + b_ih0 (48 rows); biases ----------
  h0s[tid] = aload(ws + WS_AV + tid);
  __syncthreads();
  {
    f4 hc[4];
#pragma unroll
    for (int k = 0; k < 4; ++k) hc[k] = *(const f4*)&h0s[256 * k + 4 * lane];
#pragma unroll
    for (int jj = 0; jj < 3; ++jj) {
      int j = 3 * w + jj;  // j = gate*16 + e
      int gate = j >> 4, e = j & 15;
      int row = gate * CC + eb + e;
      const float* wr = w_ih0 + (size_t)row * CC;
      float p = 0.f;
#pragma unroll
      for (int k = 0; k < 4; ++k) p += dot4(*(const f4*)(wr + 256 * k + 4 * lane), hc[k]);
#pragma unroll
      for (int off = 32; off; off >>= 1) p += __shfl_xor(p, off, 64);
      if (lane == 0) cgi0[j] = p + b_ih0[row];
    }
  }
  if (tid < 48) {
    int gate = tid >> 4, e = tid & 15;
    int row = gate * CC + eb + e;
    cbh0[tid] = b_hh0[row];
    cbh1[tid] = b_hh1[row];
    cbi1[tid] = b_ih1[row];
  }

  // ---------- A-weights (W_hh0, 3 gate rows of eg) -> VGPRs (48 regs, pinned) ----------
  f4 Wa[12];
#pragma unroll
  for (int G = 0; G < 3; ++G) {
    const float* wr = w_hh0 + ((size_t)(G * CC + eg) << 10);
#pragma unroll
    for (int k = 0; k < 4; ++k) Wa[G * 4 + k] = *(const f4*)(wr + 256 * k + 4 * lane);
  }
  // B/C weight row base pointers (streamed from L2 each tick, plain cached loads)
  const float* wc0 = w_ih1 + ((size_t)(0 * CC + eg) << 10) + 4 * lane;
  const float* wc1 = w_ih1 + ((size_t)(1 * CC + eg) << 10) + 4 * lane;
  const float* wc2 = w_ih1 + ((size_t)(2 * CC + eg) << 10) + 4 * lane;
  const float* wb0 = w_hh1 + ((size_t)(0 * CC + eg) << 10) + 4 * lane;
  const float* wb1 = w_hh1 + ((size_t)(1 * CC + eg) << 10) + 4 * lane;
  const float* wb2 = w_hh1 + ((size_t)(2 * CC + eg) << 10) + 4 * lane;

  h0s[tid] = 0.f;
  h1s[tid] = 0.f;
  __syncthreads();

  // ---------- skewed recurrence: tick tau -> h0[tau] (A, early) and h1[tau-1] (B/C, late) ----------
  float h0last = 0.f;
  u2v pd0, pd1;  // pend packet loads (element tid)

  for (int tau = 0; tau <= LL; ++tau) {
    PIN12;
    // (1) poll h0 tag tau (parity tau&1) -> h0s[tid]; then issue h1 pend
    if (tau > 0) {
      const unsigned ut = (unsigned)tau;
      const unsigned* p0 = ws_u + (tau & 1) * PKT_PAR + 2 * tid;
      vm0();  // pend (issued end of last tick) arrived
      while (pd0.y != ut) {
        npause();
        pd0 = ld8v(p0);
        vm0();
      }
      h0s[tid] = __uint_as_float(pd0.x);
      pd1 = ld8v(ws_u + H1_BASE + (tau & 1) * PKT_PAR + 2 * tid);
    }
    __syncthreads();  // S1: h0s ready

    // (2) A-phase: 3 VGPR dots -> h0[tau]; publish immediately
    float h0new = 0.f;
    if (tau < LL) {
      f4 hc0[4];
#pragma unroll
      for (int k = 0; k < 4; ++k) hc0[k] = *(const f4*)&h0s[256 * k + 4 * lane];
      float pA[3];
#pragma unroll
      for (int G = 0; G < 3; ++G) {
        float p = 0.f;
#pragma unroll
        for (int k = 0; k < 4; ++k) p += dot4(Wa[G * 4 + k], hc0[k]);
        pA[G] = p;
      }
#pragma unroll
      for (int off = 32; off; off >>= 1) {
#pragma unroll
        for (int i = 0; i < 3; ++i) pA[i] += __shfl_xor(pA[i], off, 64);
      }
      float h0prev = h0s[eg];
      float r0 = sigm(cgi0[w] + pA[0] + cbh0[w]);
      float z0 = sigm(cgi0[16 + w] + pA[1] + cbh0[16 + w]);
      float n0 = tanh_(cgi0[32 + w] + r0 * (pA[2] + cbh0[32 + w]));
      h0new = (1.f - z0) * n0 + z0 * h0prev;
      if (tau == LL - 1) h0last = h0new;
      if (lane == 0)
        pub8(ws_u + ((tau + 1) & 1) * PKT_PAR + 2 * eg, __float_as_uint(h0new),
             (unsigned)(tau + 1));
    }

    // (3) poll h1 tag tau -> h1s[tid] (published a full tick ago; usually instant)
    if (tau > 0) {
      const unsigned ut = (unsigned)tau;
      const unsigned* p1 = ws_u + H1_BASE + (tau & 1) * PKT_PAR + 2 * tid;
      vm0();
      while (pd1.y != ut) {
        npause();
        pd1 = ld8v(p1);
        vm0();
      }
      h1s[tid] = __uint_as_float(pd1.x);
    }
    __syncthreads();  // S2: h1s ready (A-phase h0s reads done too)

    // (4) B/C phase: h1[tau-1] = gru1(h0[tau-1] via C-dots, h1[tau-2] via B-dots)
    if (tau >= 1) {
      f4 hc0[4], hc1[4];
#pragma unroll
      for (int k = 0; k < 4; ++k) {
        hc0[k] = *(const f4*)&h0s[256 * k + 4 * lane];
        hc1[k] = *(const f4*)&h1s[256 * k + 4 * lane];
      }
      float pC[3], pB[3];
      {
        float c0 = 0.f, c1 = 0.f, c2 = 0.f, b0 = 0.f, b1 = 0.f, b2 = 0.f;
#pragma unroll
        for (int k = 0; k < 4; ++k) {
          int o = 256 * k;
          c0 += dot4(*(const f4*)(wc0 + o), hc0[k]);
          c1 += dot4(*(const f4*)(wc1 + o), hc0[k]);
          c2 += dot4(*(const f4*)(wc2 + o), hc0[k]);
          b0 += dot4(*(const f4*)(wb0 + o), hc1[k]);
          b1 += dot4(*(const f4*)(wb1 + o), hc1[k]);
          b2 += dot4(*(const f4*)(wb2 + o), hc1[k]);
        }
        pC[0] = c0; pC[1] = c1; pC[2] = c2;
        pB[0] = b0; pB[1] = b1; pB[2] = b2;
      }
#pragma unroll
      for (int off = 32; off; off >>= 1) {
#pragma unroll
        for (int i = 0; i < 3; ++i) {
          pC[i] += __shfl_xor(pC[i], off, 64);
          pB[i] += __shfl_xor(pB[i], off, 64);
        }
      }
      float h1prev = h1s[eg];
      float r1 = sigm(pC[0] + cbi1[w] + pB[0] + cbh1[w]);
      float z1 = sigm(pC[1] + cbi1[16 + w] + pB[1] + cbh1[16 + w]);
      float n1 = tanh_(pC[2] + cbi1[32 + w] + r1 * (pB[2] + cbh1[32 + w]));
      float h1new = (1.f - z1) * n1 + z1 * h1prev;
      if (lane == 0) {
        if (tau < LL)
          pub8(ws_u + H1_BASE + ((tau + 1) & 1) * PKT_PAR + 2 * eg,
               __float_as_uint(h1new), (unsigned)(tau + 1));
        out[(size_t)(tau - 1) * CC + eg] = h1new;
        if (tau == LL) {
          out[(size_t)LL * CC + eg] = h0last;
          out[(size_t)LL * CC + CC + eg] = h1new;
        }
      }
    } else if (lane == 0) {
      // tau==0: publish h1[-1] = 0 with tag 1
      pub8(ws_u + H1_BASE + 1 * PKT_PAR + 2 * eg, 0u, 1u);
    }

    // (5) pend h0 prefetch for next tick
    if (tau < LL) pd0 = ld8v(ws_u + ((tau + 1) & 1) * PKT_PAR + 2 * tid);
    __syncthreads();  // S3: protect h0s/h1s from next tick's stage writes
  }
}

extern "C" void kernel_launch(void* const* d_in, const int* in_sizes, int n_in,
                              void* d_out, int out_size, void* d_ws, size_t ws_size,
                              hipStream_t stream) {
  const float* x = (const float*)d_in[0];
  const float* attn_w = (const float*)d_in[1];
  const float* w_ih0 = (const float*)d_in[3];
  const float* w_hh0 = (const float*)d_in[4];
  const float* b_ih0 = (const float*)d_in[5];
  const float* b_hh0 = (const float*)d_in[6];
  const float* w_ih1 = (const float*)d_in[7];
  const float* w_hh1 = (const float*)d_in[8];
  const float* b_ih1 = (const float*)d_in[9];
  const float* b_hh1 = (const float*)d_in[10];
  float* out = (float*)d_out;
  float* ws = (float*)d_ws;

  // zero packet tags + gbar flags every call (tags start at 1 => 0 invalid; no ABA)
  hipMemsetAsync(d_ws, 0, WS_MEMSET_BYTES, stream);

  void* args[] = {&x,     &attn_w, &w_ih0, &w_hh0, &b_ih0, &b_hh0,
                  &w_ih1, &w_hh1,  &b_ih1, &b_hh1, &out,   &ws};
  hipLaunchCooperativeKernel((void*)decoder_kernel, dim3(NWG), dim3(NT), args, 0,
                             stream);
}

// Round 13
// 8574.390 us; speedup vs baseline: 2.7198x; 2.7198x over previous
//
#include <hip/hip_runtime.h>
#include <math.h>

#define CC 1024
#define LL 2048
#define NWG 256
#define NT 256

typedef float f4 __attribute__((ext_vector_type(4)));
typedef unsigned u4 __attribute__((ext_vector_type(4)));
typedef unsigned u2v __attribute__((ext_vector_type(2)));

// ws word layout:
// [0 .. 4095]     h0 packets: 2 parities x 1024 elems x 2 words (val, tag) [memset 0]
// [4096 .. 8191]  h1 packets: same layout                                  [memset 0]
// [8192..16383]   gbar arrival epochs (256 x 32 words, 128B lines)         [memset 0]
// [16384]         gbar release epoch                                       [memset 0]
// [16448..18495]  logits[2048]
// [18496..19519]  av[1024]
// tag = tau+1 written at tick tau into parity (tau+1)&1; exact-match poll.
#define H1_BASE 4096
#define PKT_PAR 2048
#define WS_FLAGS 8192
#define WS_REL 16384
#define WS_LOGITS 16448
#define WS_AV (WS_LOGITS + LL)
#define WS_MEMSET_BYTES ((WS_REL + 64) * 4)

__device__ __forceinline__ float aload(const float* p) {
  return __hip_atomic_load(p, __ATOMIC_RELAXED, __HIP_MEMORY_SCOPE_AGENT);
}
__device__ __forceinline__ void astore(float* p, float v) {
  __hip_atomic_store(p, v, __ATOMIC_RELAXED, __HIP_MEMORY_SCOPE_AGENT);
}
__device__ __forceinline__ float sigm(float x) { return 1.0f / (1.0f + __expf(-x)); }
__device__ __forceinline__ float tanh_(float x) { return 2.0f / (1.0f + __expf(-2.0f * x)) - 1.0f; }
__device__ __forceinline__ float dot4(f4 a, f4 b) {
  return fmaf(a.x, b.x, fmaf(a.y, b.y, fmaf(a.z, b.z, a.w * b.w)));
}

// L2-bypass ops (coherence at L3)
__device__ __forceinline__ u4 ld16v(const unsigned* p) {  // issue only, no wait
  u4 r;
  asm volatile("global_load_dwordx4 %0, %1, off sc0 sc1" : "=v"(r) : "v"(p) : "memory");
  return r;
}
__device__ __forceinline__ void vm0() { asm volatile("s_waitcnt vmcnt(0)" ::: "memory"); }
__device__ __forceinline__ void vm1() { asm volatile("s_waitcnt vmcnt(1)" ::: "memory"); }
// publish: 8B (val,tag) single-copy-atomic store, untracked by compiler vmcnt bookkeeping
__device__ __forceinline__ void st8u(unsigned* p, unsigned val, unsigned tag) {
  u2v v;
  v.x = val;
  v.y = tag;
  asm volatile("global_store_dwordx2 %0, %1, off sc0 sc1" ::"v"(p), "v"(v) : "memory");
}

// prologue-only arrival-slot barrier (relaxed spins + one acquire)
__device__ __forceinline__ void gbar(unsigned* ws_u, unsigned epoch) {
  __syncthreads();
  if (blockIdx.x == 0) {
    const int i = threadIdx.x;
    if (i > 0 && i < NWG) {
      unsigned* slot = ws_u + WS_FLAGS + i * 32;
      while (__hip_atomic_load(slot, __ATOMIC_RELAXED, __HIP_MEMORY_SCOPE_AGENT) < epoch) {
      }
      (void)__hip_atomic_load(slot, __ATOMIC_ACQUIRE, __HIP_MEMORY_SCOPE_AGENT);
    }
    __syncthreads();
    if (i == 0)
      __hip_atomic_store(ws_u + WS_REL, epoch, __ATOMIC_RELEASE, __HIP_MEMORY_SCOPE_AGENT);
    __syncthreads();
  } else {
    if (threadIdx.x == 0) {
      __hip_atomic_store(ws_u + WS_FLAGS + blockIdx.x * 32, epoch, __ATOMIC_RELEASE,
                         __HIP_MEMORY_SCOPE_AGENT);
      unsigned* rel = ws_u + WS_REL;
      while (__hip_atomic_load(rel, __ATOMIC_RELAXED, __HIP_MEMORY_SCOPE_AGENT) < epoch) {
      }
      (void)__hip_atomic_load(rel, __ATOMIC_ACQUIRE, __HIP_MEMORY_SCOPE_AGENT);
    }
    __syncthreads();
  }
}

#define PIN12                                                                        \
  asm volatile("" : "+v"(Wa[0]), "+v"(Wa[1]), "+v"(Wa[2]), "+v"(Wa[3]), "+v"(Wa[4]), \
                    "+v"(Wa[5]), "+v"(Wa[6]), "+v"(Wa[7]), "+v"(Wa[8]), "+v"(Wa[9]), \
                    "+v"(Wa[10]), "+v"(Wa[11]))

__global__ __launch_bounds__(NT, 1) void decoder_kernel(
    const float* __restrict__ x, const float* __restrict__ attn_w,
    const float* __restrict__ w_ih0, const float* __restrict__ w_hh0,
    const float* __restrict__ b_ih0, const float* __restrict__ b_hh0,
    const float* __restrict__ w_ih1, const float* __restrict__ w_hh1,
    const float* __restrict__ b_ih1, const float* __restrict__ b_hh1,
    float* __restrict__ out, float* __restrict__ ws) {
  const int g = blockIdx.x;
  const int tid = threadIdx.x;
  const int lane = tid & 63;
  const int w = tid >> 6;
  const int eg = 4 * g + w;  // element owned by this wave

  unsigned* ws_u = (unsigned*)ws;

  extern __shared__ float wcb[];  // 24 rows x 1024 f32 = 96 KB: wave w rows at (w*6+idx)
                                  // idx 0..2 = W_ih1 gates (C), 3..5 = W_hh1 gates (B)
  __shared__ __align__(16) float h0s[2][CC];  // parity-indexed h-state (no tail barrier)
  __shared__ __align__(16) float h1s[2][CC];
  __shared__ float cgi0[12], cbh0[12], cbh1[12], cbi1[12];
  __shared__ float red[NT];

  // ---------- P0: logits[t] = dot(w2, x[t]) ----------
  {
    const float* w2 = attn_w + CC;
#pragma unroll
    for (int s = 0; s < 2; ++s) {
      int t = 8 * g + 2 * w + s;
      const float* xr = x + (size_t)t * CC;
      float p = 0.f;
#pragma unroll
      for (int k = 0; k < 4; ++k) {
        f4 xa = *(const f4*)(xr + 256 * k + 4 * lane);
        f4 wa = *(const f4*)(w2 + 256 * k + 4 * lane);
        p += dot4(xa, wa);
      }
#pragma unroll
      for (int off = 32; off; off >>= 1) p += __shfl_xor(p, off, 64);
      if (lane == 0) astore(ws + WS_LOGITS + t, p);
    }
  }
  gbar(ws_u, 1);

  // ---------- P1: softmax over L, av columns [4g,4g+4) ----------
  {
    float myl[8];
#pragma unroll
    for (int s = 0; s < 8; ++s) myl[s] = aload(ws + WS_LOGITS + tid + 256 * s);
    float lm = myl[0];
#pragma unroll
    for (int s = 1; s < 8; ++s) lm = fmaxf(lm, myl[s]);
    red[tid] = lm;
    __syncthreads();
    for (int stp = 128; stp; stp >>= 1) {
      if (tid < stp) red[tid] = fmaxf(red[tid], red[tid + stp]);
      __syncthreads();
    }
    float m = red[0];
    __syncthreads();
    float myw[8];
    float ls = 0.f;
#pragma unroll
    for (int s = 0; s < 8; ++s) {
      myw[s] = __expf(myl[s] - m);
      ls += myw[s];
    }
    red[tid] = ls;
    __syncthreads();
    for (int stp = 128; stp; stp >>= 1) {
      if (tid < stp) red[tid] += red[tid + stp];
      __syncthreads();
    }
    float invZ = 1.0f / red[0];
    __syncthreads();
    float acc[4] = {0.f, 0.f, 0.f, 0.f};
#pragma unroll
    for (int s = 0; s < 8; ++s) {
      int t = tid + 256 * s;
      f4 xa = *(const f4*)(x + (size_t)t * CC + 4 * g);
      acc[0] = fmaf(myw[s], xa.x, acc[0]);
      acc[1] = fmaf(myw[s], xa.y, acc[1]);
      acc[2] = fmaf(myw[s], xa.z, acc[2]);
      acc[3] = fmaf(myw[s], xa.w, acc[3]);
    }
    for (int i = 0; i < 4; ++i) {
      red[tid] = acc[i];
      __syncthreads();
      for (int stp = 128; stp; stp >>= 1) {
        if (tid < stp) red[tid] += red[tid + stp];
        __syncthreads();
      }
      if (tid == 0) astore(ws + WS_AV + 4 * g + i, red[0] * invZ);
      __syncthreads();
    }
  }
  gbar(ws_u, 2);

  // ---------- P2: gi0 = W_ih0 . av + b_ih0 (this WG's 12 rows); biases ----------
#pragma unroll
  for (int i = 0; i < 4; ++i) h0s[0][4 * tid + i] = aload(ws + WS_AV + 4 * tid + i);
  __syncthreads();
  {
    f4 hc[4];
#pragma unroll
    for (int k = 0; k < 4; ++k) hc[k] = *(const f4*)&h0s[0][256 * k + 4 * lane];
#pragma unroll
    for (int jj = 0; jj < 3; ++jj) {
      int j = 3 * w + jj;
      int gate = j >> 2, e = j & 3;
      int row = gate * CC + 4 * g + e;
      const float* wr = w_ih0 + (size_t)row * CC;
      float p = 0.f;
#pragma unroll
      for (int k = 0; k < 4; ++k) p += dot4(*(const f4*)(wr + 256 * k + 4 * lane), hc[k]);
#pragma unroll
      for (int off = 32; off; off >>= 1) p += __shfl_xor(p, off, 64);
      if (lane == 0) cgi0[j] = p + b_ih0[row];
    }
  }
  if (tid < 12) {
    int gate = tid >> 2, e = tid & 3;
    int row = gate * CC + 4 * g + e;
    cbh0[tid] = b_hh0[row];
    cbh1[tid] = b_hh1[row];
    cbi1[tid] = b_ih1[row];
  }
  __syncthreads();  // cgi0 reads of h0s[0] done before zeroing

  // ---------- A-weights (W_hh0, 3 gate rows of eg) -> VGPRs (48 regs, pinned) ----------
  f4 Wa[12];
#pragma unroll
  for (int G = 0; G < 3; ++G) {
    const float* wr = w_hh0 + ((size_t)(G * CC + eg) << 10);
#pragma unroll
    for (int k = 0; k < 4; ++k) Wa[G * 4 + k] = *(const f4*)(wr + 256 * k + 4 * lane);
  }

  // ---------- B/C weights -> LDS ----------
#pragma unroll
  for (int j = 0; j < 24; ++j) {
    int ww = j / 6, r = j % 6;
    int G = r % 3;
    const float* src = (r < 3 ? w_ih1 : w_hh1) + ((size_t)(G * CC + 4 * g + ww) << 10);
    *(f4*)&wcb[(j << 10) + 4 * tid] = *(const f4*)(src + 4 * tid);
  }
#pragma unroll
  for (int i = 0; i < 4; ++i) {
    h0s[0][4 * tid + i] = 0.f;
    h0s[1][4 * tid + i] = 0.f;
    h1s[0][4 * tid + i] = 0.f;
    h1s[1][4 * tid + i] = 0.f;
  }
  __syncthreads();

  // ---------- skewed recurrence: tick tau -> h0[tau] (A, early) and h1[tau-1] (B/C, late) ----------
  float h0last = 0.f;
  u4 pd0a, pd0b, pd1a, pd1b;  // pend packet loads
  const float* wr6 = wcb + (w * 6) * 1024;

  for (int tau = 0; tau <= LL; ++tau) {
    PIN12;
    const int p = tau & 1;
    // (1) pollA h0[tau-1] tag tau (parity p) -> h0s[p]; then issue h1 pend
    if (tau > 0) {
      const unsigned ut = (unsigned)tau;
      const unsigned* p0 = ws_u + p * PKT_PAR + 8 * tid;
      vm0();  // pend (issued during last tick's BC) arrived
      while (pd0a.y != ut || pd0a.w != ut || pd0b.y != ut || pd0b.w != ut) {
        pd0a = ld16v(p0);
        pd0b = ld16v(p0 + 4);
        vm0();
      }
      h0s[p][4 * tid + 0] = __uint_as_float(pd0a.x);
      h0s[p][4 * tid + 1] = __uint_as_float(pd0a.z);
      h0s[p][4 * tid + 2] = __uint_as_float(pd0b.x);
      h0s[p][4 * tid + 3] = __uint_as_float(pd0b.z);
      const unsigned* p1 = ws_u + H1_BASE + p * PKT_PAR + 8 * tid;
      pd1a = ld16v(p1);
      pd1b = ld16v(p1 + 4);
    }
    __syncthreads();  // S1: h0s[p] ready

    // (2) A-phase: 3 VGPR dots -> h0[tau]; publish immediately
    float h0new = 0.f;
    if (tau < LL) {
      f4 hc0[4];
#pragma unroll
      for (int k = 0; k < 4; ++k) hc0[k] = *(const f4*)&h0s[p][256 * k + 4 * lane];
      float pA[3];
#pragma unroll
      for (int G = 0; G < 3; ++G) {
        float pp = 0.f;
#pragma unroll
        for (int k = 0; k < 4; ++k) pp += dot4(Wa[G * 4 + k], hc0[k]);
        pA[G] = pp;
      }
#pragma unroll
      for (int off = 32; off; off >>= 1) {
#pragma unroll
        for (int i = 0; i < 3; ++i) pA[i] += __shfl_xor(pA[i], off, 64);
      }
      float h0prev = h0s[p][eg];
      float r0 = sigm(cgi0[w] + pA[0] + cbh0[w]);
      float z0 = sigm(cgi0[4 + w] + pA[1] + cbh0[4 + w]);
      float n0 = tanh_(cgi0[8 + w] + r0 * (pA[2] + cbh0[8 + w]));
      h0new = (1.f - z0) * n0 + z0 * h0prev;
      if (tau == LL - 1) h0last = h0new;
      if (lane == 0)
        st8u(ws_u + (p ^ 1) * PKT_PAR + 2 * eg, __float_as_uint(h0new),
             (unsigned)(tau + 1));
    }

    // (3) pollB h1[tau-2] tag tau (parity p) -> h1s[p]
    if (tau > 0) {
      const unsigned ut = (unsigned)tau;
      const unsigned* p1 = ws_u + H1_BASE + p * PKT_PAR + 8 * tid;
      vm1();  // waits pd1a/pd1b only (publish store may still fly)
      while (pd1a.y != ut || pd1a.w != ut || pd1b.y != ut || pd1b.w != ut) {
        pd1a = ld16v(p1);
        pd1b = ld16v(p1 + 4);
        vm0();
      }
      h1s[p][4 * tid + 0] = __uint_as_float(pd1a.x);
      h1s[p][4 * tid + 1] = __uint_as_float(pd1a.z);
      h1s[p][4 * tid + 2] = __uint_as_float(pd1b.x);
      h1s[p][4 * tid + 3] = __uint_as_float(pd1b.z);
    }
    __syncthreads();  // S2: h1s[p] ready (A-phase h0s reads done too)

    // (4) BC phase with pipelined h0-pend: issue early, re-check mid-compute
    const unsigned* np = ws_u + (p ^ 1) * PKT_PAR + 8 * tid;
    if (tau < LL) {  // issue pend for next tick's pollA (flight hidden under BC)
      pd0a = ld16v(np);
      pd0b = ld16v(np + 4);
    }
    if (tau >= 1) {
      f4 hc0[4], hc1[4];
#pragma unroll
      for (int k = 0; k < 4; ++k) {
        hc0[k] = *(const f4*)&h0s[p][256 * k + 4 * lane];
        hc1[k] = *(const f4*)&h1s[p][256 * k + 4 * lane];
      }
      float pC[3];
#pragma unroll
      for (int G = 0; G < 3; ++G) {
        float pc = 0.f;
#pragma unroll
        for (int k = 0; k < 4; ++k)
          pc += dot4(*(const f4*)&wr6[G * 1024 + 256 * k + 4 * lane], hc0[k]);
        pC[G] = pc;
      }
      // mid-BC pend re-check: if stale, re-issue so tick-top check hits
      if (tau < LL) {
        const unsigned nt_ = (unsigned)(tau + 1);
        vm0();
        if (pd0a.y != nt_ || pd0a.w != nt_ || pd0b.y != nt_ || pd0b.w != nt_) {
          pd0a = ld16v(np);
          pd0b = ld16v(np + 4);
        }
      }
      float pB[3];
#pragma unroll
      for (int G = 0; G < 3; ++G) {
        float pb = 0.f;
#pragma unroll
        for (int k = 0; k < 4; ++k)
          pb += dot4(*(const f4*)&wr6[(3 + G) * 1024 + 256 * k + 4 * lane], hc1[k]);
        pB[G] = pb;
      }
#pragma unroll
      for (int off = 32; off; off >>= 1) {
#pragma unroll
        for (int i = 0; i < 3; ++i) {
          pC[i] += __shfl_xor(pC[i], off, 64);
          pB[i] += __shfl_xor(pB[i], off, 64);
        }
      }
      float h1prev = h1s[p][eg];
      float r1 = sigm(pC[0] + cbi1[w] + pB[0] + cbh1[w]);
      float z1 = sigm(pC[1] + cbi1[4 + w] + pB[1] + cbh1[4 + w]);
      float n1 = tanh_(pC[2] + cbi1[8 + w] + r1 * (pB[2] + cbh1[8 + w]));
      float h1new = (1.f - z1) * n1 + z1 * h1prev;
      if (lane == 0) {
        if (tau < LL)
          st8u(ws_u + H1_BASE + (p ^ 1) * PKT_PAR + 2 * eg, __float_as_uint(h1new),
               (unsigned)(tau + 1));
        out[(size_t)(tau - 1) * CC + eg] = h1new;
        if (tau == LL) {
          out[(size_t)LL * CC + eg] = h0last;
          out[(size_t)LL * CC + CC + eg] = h1new;
        }
      }
    } else if (lane == 0) {
      // tau==0: publish h1[-1] = 0 with tag 1 (parity 1)
      st8u(ws_u + H1_BASE + 1 * PKT_PAR + 2 * eg, 0u, 1u);
    }
    // no tail barrier: next tick writes h0s[p^1]/h1s[p^1], disjoint from this
    // tick's reads of h0s[p]/h1s[p]; S1/S2 of tick tau+1 fence the tau+2 reuse.
  }
}

extern "C" void kernel_launch(void* const* d_in, const int* in_sizes, int n_in,
                              void* d_out, int out_size, void* d_ws, size_t ws_size,
                              hipStream_t stream) {
  const float* x = (const float*)d_in[0];
  const float* attn_w = (const float*)d_in[1];
  const float* w_ih0 = (const float*)d_in[3];
  const float* w_hh0 = (const float*)d_in[4];
  const float* b_ih0 = (const float*)d_in[5];
  const float* b_hh0 = (const float*)d_in[6];
  const float* w_ih1 = (const float*)d_in[7];
  const float* w_hh1 = (const float*)d_in[8];
  const float* b_ih1 = (const float*)d_in[9];
  const float* b_hh1 = (const float*)d_in[10];
  float* out = (float*)d_out;
  float* ws = (float*)d_ws;

  static int attr_set = 0;
  if (!attr_set) {
    hipFuncSetAttribute((const void*)decoder_kernel,
                        hipFuncAttributeMaxDynamicSharedMemorySize, 24 * 1024 * 4);
    attr_set = 1;
  }

  // zero packet tags + gbar flags every call (tags start at 1 => 0 invalid; no ABA)
  hipMemsetAsync(d_ws, 0, WS_MEMSET_BYTES, stream);

  void* args[] = {&x,     &attn_w, &w_ih0, &w_hh0, &b_ih0, &b_hh0,
                  &w_ih1, &w_hh1,  &b_ih1, &b_hh1, &out,   &ws};
  hipLaunchCooperativeKernel((void*)decoder_kernel, dim3(NWG), dim3(NT), args,
                             24 * 1024 * 4, stream);
}